// Round 1
// baseline (364.668 us; speedup 1.0000x reference)
//
#include <hip/hip_runtime.h>

#define BB 32
#define TT 128
#define PP 512
#define DD 300
#define NPK 7168   // P*ND*MAXL = 512*2*7
#define NEG -1e30f

// ---------------------------------------------------------------------------
// Phase 1: ts[m][n] = dot(emb_table[tokens[m]], diags[n]) + bias[n]
// M=4096 (b*T+t), N=7168 (p*14 + nd*7 + l), K=300. fp32, 128x128 tile,
// 8x8 per thread. A-rows gathered via tokens.
// ---------------------------------------------------------------------------
__global__ __launch_bounds__(256) void gemm_kernel(
    const int* __restrict__ tokens,
    const float* __restrict__ emb,
    const float* __restrict__ diags,
    const float* __restrict__ bias,
    float* __restrict__ C)
{
    // k-major LDS tiles, stride 132 (132%32==4 -> 2-way max on transpose store, free)
    __shared__ __align__(16) float As[16][132];
    __shared__ __align__(16) float Bs[16][132];
    __shared__ int rowbase[128];

    const int tid = threadIdx.x;
    const int n0 = blockIdx.x * 128;
    const int m0 = blockIdx.y * 128;

    if (tid < 128) rowbase[tid] = tokens[m0 + tid] * DD;
    __syncthreads();

    const int tx4 = (tid & 15) * 4;
    const int ty4 = (tid >> 4) * 4;
    const int r0  = tid >> 2;        // 0..63
    const int kq  = (tid & 3) * 4;   // 0,4,8,12

    float acc[8][8];
    #pragma unroll
    for (int i = 0; i < 8; ++i)
        #pragma unroll
        for (int j = 0; j < 8; ++j) acc[i][j] = 0.f;

    for (int kk = 0; kk < DD; kk += 16) {
        float4 a0, a1, b0, b1;
        const bool kval = (kk + kq) < DD;   // 300 % 4 == 0 -> float4-granular guard
        if (kval) {
            a0 = *(const float4*)(emb + rowbase[r0] + kk + kq);
            a1 = *(const float4*)(emb + rowbase[r0 + 64] + kk + kq);
            b0 = *(const float4*)(diags + (size_t)(n0 + r0) * DD + kk + kq);
            b1 = *(const float4*)(diags + (size_t)(n0 + r0 + 64) * DD + kk + kq);
        } else {
            a0 = make_float4(0.f, 0.f, 0.f, 0.f);
            a1 = a0; b0 = a0; b1 = a0;
        }
        __syncthreads();
        As[kq + 0][r0] = a0.x; As[kq + 1][r0] = a0.y; As[kq + 2][r0] = a0.z; As[kq + 3][r0] = a0.w;
        As[kq + 0][r0 + 64] = a1.x; As[kq + 1][r0 + 64] = a1.y; As[kq + 2][r0 + 64] = a1.z; As[kq + 3][r0 + 64] = a1.w;
        Bs[kq + 0][r0] = b0.x; Bs[kq + 1][r0] = b0.y; Bs[kq + 2][r0] = b0.z; Bs[kq + 3][r0] = b0.w;
        Bs[kq + 0][r0 + 64] = b1.x; Bs[kq + 1][r0 + 64] = b1.y; Bs[kq + 2][r0 + 64] = b1.z; Bs[kq + 3][r0 + 64] = b1.w;
        __syncthreads();
        #pragma unroll
        for (int k = 0; k < 16; ++k) {
            float4 av0 = *(const float4*)&As[k][ty4];
            float4 av1 = *(const float4*)&As[k][ty4 + 64];
            float4 bv0 = *(const float4*)&Bs[k][tx4];
            float4 bv1 = *(const float4*)&Bs[k][tx4 + 64];
            float a[8] = {av0.x, av0.y, av0.z, av0.w, av1.x, av1.y, av1.z, av1.w};
            float b[8] = {bv0.x, bv0.y, bv0.z, bv0.w, bv1.x, bv1.y, bv1.z, bv1.w};
            #pragma unroll
            for (int i = 0; i < 8; ++i)
                #pragma unroll
                for (int j = 0; j < 8; ++j)
                    acc[i][j] = fmaf(a[i], b[j], acc[i][j]);
        }
    }

    const float4 bias0 = *(const float4*)(bias + n0 + tx4);
    const float4 bias1 = *(const float4*)(bias + n0 + 64 + tx4);
    #pragma unroll
    for (int i = 0; i < 8; ++i) {
        const int m = m0 + ((i < 4) ? (ty4 + i) : (64 + ty4 + (i - 4)));
        float4 lo = make_float4(acc[i][0] + bias0.x, acc[i][1] + bias0.y,
                                acc[i][2] + bias0.z, acc[i][3] + bias0.w);
        float4 hi = make_float4(acc[i][4] + bias1.x, acc[i][5] + bias1.y,
                                acc[i][6] + bias1.z, acc[i][7] + bias1.w);
        *(float4*)(C + (size_t)m * NPK + n0 + tx4) = lo;
        *(float4*)(C + (size_t)m * NPK + n0 + 64 + tx4) = hi;
    }
}

// ---------------------------------------------------------------------------
// Phase 2: max-sum semiring scan over t. One thread per (b, pattern).
// hid[7] in registers; reads 14 floats per t (prefetched one step ahead).
// ---------------------------------------------------------------------------
__global__ __launch_bounds__(128) void scan_kernel(
    const float* __restrict__ ts,
    const float* __restrict__ epsilons,
    const int* __restrict__ doc_lens,
    float* __restrict__ scores)
{
    const int b = blockIdx.x;
    const int p = blockIdx.y * 128 + threadIdx.x;
    const int dl = doc_lens[b];

    float e[6];
    #pragma unroll
    for (int i = 0; i < 6; ++i) e[i] = epsilons[p * 6 + i];

    const float* base = ts + (size_t)b * TT * NPK + p * 14;

    float h0 = 0.f, h1 = NEG, h2 = NEG, h3 = NEG, h4 = NEG, h5 = NEG, h6 = NEG;
    float sc = NEG;
    const bool end5 = (p < 256);   // patterns 0..255 have end state 5, rest 6

    float buf0[14], buf1[14];

    auto load = [&](float* buf, int t) {
        const float2* s = (const float2*)(base + (size_t)t * NPK);
        #pragma unroll
        for (int i = 0; i < 7; ++i) ((float2*)buf)[i] = s[i];
    };
    auto step = [&](const float* tm, int t) {
        // ae[l] = max(hid[l], hid[l-1] + eps[l-1]);  ae[0] = hid[0]
        float ae0 = h0;
        float ae1 = fmaxf(h1, h0 + e[0]);
        float ae2 = fmaxf(h2, h1 + e[1]);
        float ae3 = fmaxf(h3, h2 + e[2]);
        float ae4 = fmaxf(h4, h3 + e[3]);
        float ae5 = fmaxf(h5, h4 + e[4]);
        float ae6 = fmaxf(h6, h5 + e[5]);
        // hid[l] = max( main[l], sl[l] ); main[0]=0(restart), main[l]=ae[l-1]+tm[1][l-1]
        // sl[l] = ae[l] + tm[0][l].  tm layout: [0..6]=diag0(self), [7..13]=diag1(main)
        h0 = fmaxf(0.f,           ae0 + tm[0]);
        h1 = fmaxf(ae0 + tm[7],   ae1 + tm[1]);
        h2 = fmaxf(ae1 + tm[8],   ae2 + tm[2]);
        h3 = fmaxf(ae2 + tm[9],   ae3 + tm[3]);
        h4 = fmaxf(ae3 + tm[10],  ae4 + tm[4]);
        h5 = fmaxf(ae4 + tm[11],  ae5 + tm[5]);
        h6 = fmaxf(ae5 + tm[12],  ae6 + tm[6]);
        const float endv = end5 ? h5 : h6;
        if (t < dl) sc = fmaxf(sc, endv);
    };

    load(buf0, 0);
    for (int t = 0; t < TT; t += 2) {
        load(buf1, t + 1);
        step(buf0, t);
        if (t + 2 < TT) load(buf0, t + 2);
        step(buf1, t + 1);
    }

    scores[p * BB + b] = sc;   // [P][B] layout for phase 3
}

// ---------------------------------------------------------------------------
// Phase 3: BatchNorm (batch stats) + sign(relu) + final linear. One block.
// ---------------------------------------------------------------------------
__global__ __launch_bounds__(512) void finalize_kernel(
    const float* __restrict__ scores,
    const float* __restrict__ bn_w,
    const float* __restrict__ bn_b,
    const float* __restrict__ fw,
    const float* __restrict__ fb,
    float* __restrict__ out)
{
    __shared__ float acc[64];
    const int p = threadIdx.x;
    if (p < 64) acc[p] = 0.f;
    __syncthreads();

    float x[32];
    const float4* sp = (const float4*)(scores + p * 32);
    #pragma unroll
    for (int i = 0; i < 8; ++i) ((float4*)x)[i] = sp[i];

    float mean = 0.f;
    #pragma unroll
    for (int i = 0; i < 32; ++i) mean += x[i];
    mean *= (1.f / 32.f);
    float var = 0.f;
    #pragma unroll
    for (int i = 0; i < 32; ++i) { const float d = x[i] - mean; var = fmaf(d, d, var); }
    var *= (1.f / 32.f);

    const float scale = (1.f / sqrtf(var + 1e-5f)) * bn_w[p];
    const float shift = bn_b[p];
    const float w0 = fw[p], w1 = fw[PP + p];

    for (int b = 0; b < 32; ++b) {
        const float v = (x[b] - mean) * scale + shift;
        const bool bin = v > 0.f;      // sign(relu(v))
        float v0 = bin ? w0 : 0.f;
        float v1 = bin ? w1 : 0.f;
        #pragma unroll
        for (int o = 32; o; o >>= 1) {
            v0 += __shfl_xor(v0, o);
            v1 += __shfl_xor(v1, o);
        }
        if ((threadIdx.x & 63) == 0) {
            atomicAdd(&acc[b * 2 + 0], v0);
            atomicAdd(&acc[b * 2 + 1], v1);
        }
    }
    __syncthreads();
    if (p < 64) out[p] = acc[p] + fb[p & 1];
}

// ---------------------------------------------------------------------------
extern "C" void kernel_launch(void* const* d_in, const int* in_sizes, int n_in,
                              void* d_out, int out_size, void* d_ws, size_t ws_size,
                              hipStream_t stream) {
    const int*   tokens   = (const int*)d_in[0];
    const int*   doc_lens = (const int*)d_in[1];
    const float* emb      = (const float*)d_in[2];
    const float* diags    = (const float*)d_in[3];
    const float* bias     = (const float*)d_in[4];
    const float* eps      = (const float*)d_in[5];
    const float* bnw      = (const float*)d_in[6];
    const float* bnb      = (const float*)d_in[7];
    const float* fw       = (const float*)d_in[8];
    const float* fb       = (const float*)d_in[9];
    float* out = (float*)d_out;

    float* ts = (float*)d_ws;                           // [4096][7168] = 117.4 MB
    float* scores = ts + (size_t)4096 * NPK;            // [512][32]

    gemm_kernel<<<dim3(56, 32), 256, 0, stream>>>(tokens, emb, diags, bias, ts);
    scan_kernel<<<dim3(32, 4), 128, 0, stream>>>(ts, eps, doc_lens, scores);
    finalize_kernel<<<1, 512, 0, stream>>>(scores, bnw, bnb, fw, fb, out);
}

// Round 2
// 215.787 us; speedup vs baseline: 1.6899x; 1.6899x over previous
//
#include <hip/hip_runtime.h>

#define BB 32
#define TT 128
#define PP 512
#define DD 300
#define NPK 7168   // P*ND*MAXL = 512*2*7
#define KP 320     // K padded to multiple of 32
#define NEG -1e30f

typedef _Float16 half8 __attribute__((ext_vector_type(8)));
typedef _Float16 half4 __attribute__((ext_vector_type(4)));
typedef float floatx4 __attribute__((ext_vector_type(4)));

__device__ __forceinline__ void async_load16(const void* g, void* l) {
    __builtin_amdgcn_global_load_lds(
        (const __attribute__((address_space(1))) void*)g,
        (__attribute__((address_space(3))) void*)l, 16, 0, 0);
}

__device__ __forceinline__ floatx4 mfma16(half8 a, half8 b, floatx4 c) {
    return __builtin_amdgcn_mfma_f32_16x16x32_f16(a, b, c, 0, 0, 0);
}

// ---------------------------------------------------------------------------
// Pack kernels: error-free f16 Dekker split. x = hi + lo*2^-12 (lo stored
// pre-scaled by 4096 so it stays in f16 normal range). Residual ~2^-24|x|.
// ---------------------------------------------------------------------------
__global__ __launch_bounds__(256) void pack_a_kernel(
    const int* __restrict__ tokens, const float* __restrict__ emb,
    _Float16* __restrict__ Ah, _Float16* __restrict__ Al)
{
    const int idx = blockIdx.x * 256 + threadIdx.x;
    if (idx >= 4096 * 80) return;
    const int m = idx / 80;
    const int c = idx - m * 80;
    float4 x = make_float4(0.f, 0.f, 0.f, 0.f);
    if (c < 75) x = *(const float4*)(emb + (size_t)tokens[m] * DD + c * 4);
    half4 h, l;
    h.x = (_Float16)x.x; l.x = (_Float16)((x.x - (float)h.x) * 4096.f);
    h.y = (_Float16)x.y; l.y = (_Float16)((x.y - (float)h.y) * 4096.f);
    h.z = (_Float16)x.z; l.z = (_Float16)((x.z - (float)h.z) * 4096.f);
    h.w = (_Float16)x.w; l.w = (_Float16)((x.w - (float)h.w) * 4096.f);
    *(half4*)(Ah + (size_t)m * KP + c * 4) = h;
    *(half4*)(Al + (size_t)m * KP + c * 4) = l;
}

__global__ __launch_bounds__(256) void pack_b_kernel(
    const float* __restrict__ diags,
    _Float16* __restrict__ Bh, _Float16* __restrict__ Bl)
{
    const int idx = blockIdx.x * 256 + threadIdx.x;
    if (idx >= NPK * 80) return;
    const int n = idx / 80;
    const int c = idx - n * 80;
    float4 x = make_float4(0.f, 0.f, 0.f, 0.f);
    if (c < 75) x = *(const float4*)(diags + (size_t)n * DD + c * 4);
    half4 h, l;
    h.x = (_Float16)x.x; l.x = (_Float16)((x.x - (float)h.x) * 4096.f);
    h.y = (_Float16)x.y; l.y = (_Float16)((x.y - (float)h.y) * 4096.f);
    h.z = (_Float16)x.z; l.z = (_Float16)((x.z - (float)h.z) * 4096.f);
    h.w = (_Float16)x.w; l.w = (_Float16)((x.w - (float)h.w) * 4096.f);
    *(half4*)(Bh + (size_t)n * KP + c * 4) = h;
    *(half4*)(Bl + (size_t)n * KP + c * 4) = l;
}

// ---------------------------------------------------------------------------
// MFMA GEMM: ts[m][n] = sum_k A[m][k]*B[n][k] + bias[n] via 3-product f16
// split. 128x128 block tile, BK=32, 4 waves in 2x2 grid (64x64 per wave),
// 16x16x32 MFMA, global_load_lds(16B) staging, m97 2-barrier K-loop.
// ---------------------------------------------------------------------------
__global__ __launch_bounds__(256, 2) void gemm_f16_kernel(
    const _Float16* __restrict__ Ah, const _Float16* __restrict__ Al,
    const _Float16* __restrict__ Bh, const _Float16* __restrict__ Bl,
    const float* __restrict__ bias, float* __restrict__ C)
{
    __shared__ __align__(16) _Float16 AsH[128 * 32];
    __shared__ __align__(16) _Float16 AsL[128 * 32];
    __shared__ __align__(16) _Float16 BsH[128 * 32];
    __shared__ __align__(16) _Float16 BsL[128 * 32];

    const int tid = threadIdx.x;
    const int w = tid >> 6, ln = tid & 63;
    const int n0 = blockIdx.x * 128, m0 = blockIdx.y * 128;
    const int wm = w & 1, wn = w >> 1;

    floatx4 acc0[4][4], acc1[4][4];
    #pragma unroll
    for (int i = 0; i < 4; ++i)
        #pragma unroll
        for (int j = 0; j < 4; ++j) {
            acc0[i][j] = (floatx4){0.f, 0.f, 0.f, 0.f};
            acc1[i][j] = (floatx4){0.f, 0.f, 0.f, 0.f};
        }

    const int lrow = ln >> 2;   // 0..15: row within 16-row staging segment
    const int lkc  = ln & 3;    // 16-byte chunk within 64-byte k-row
    const int fr   = ln & 15;   // fragment row (m or n within 16-tile)
    const int kg   = ln >> 4;   // k-group 0..3

    for (int kt = 0; kt < KP / 32; ++kt) {
        const int k0 = kt * 32;
        // stage: each wave copies 2 16-row segments of each of 4 arrays
        #pragma unroll
        for (int s = 0; s < 2; ++s) {
            const int r0 = (w * 2 + s) * 16;
            const int row = r0 + lrow;
            const size_t ga = (size_t)(m0 + row) * KP + k0 + lkc * 8;
            const size_t gb = (size_t)(n0 + row) * KP + k0 + lkc * 8;
            async_load16(Ah + ga, &AsH[r0 * 32]);
            async_load16(Al + ga, &AsL[r0 * 32]);
            async_load16(Bh + gb, &BsH[r0 * 32]);
            async_load16(Bl + gb, &BsL[r0 * 32]);
        }
        __syncthreads();

        half8 a_h[4], a_l[4];
        #pragma unroll
        for (int i = 0; i < 4; ++i) {
            const int off = (wm * 64 + i * 16 + fr) * 32 + kg * 8;
            a_h[i] = *(const half8*)&AsH[off];
            a_l[i] = *(const half8*)&AsL[off];
        }
        #pragma unroll
        for (int j = 0; j < 4; ++j) {
            const int off = (wn * 64 + j * 16 + fr) * 32 + kg * 8;
            const half8 b_h = *(const half8*)&BsH[off];
            const half8 b_l = *(const half8*)&BsL[off];
            #pragma unroll
            for (int i = 0; i < 4; ++i) {
                acc0[i][j] = mfma16(a_h[i], b_h, acc0[i][j]);
                acc1[i][j] = mfma16(a_h[i], b_l, acc1[i][j]);
                acc1[i][j] = mfma16(a_l[i], b_h, acc1[i][j]);
            }
        }
        __syncthreads();
    }

    // epilogue: C/D layout col=lane&15, row=(lane>>4)*4+reg
    #pragma unroll
    for (int j = 0; j < 4; ++j) {
        const int n = n0 + wn * 64 + j * 16 + fr;
        const float bj = bias[n];
        #pragma unroll
        for (int i = 0; i < 4; ++i) {
            const int mbase = m0 + wm * 64 + i * 16 + kg * 4;
            #pragma unroll
            for (int r = 0; r < 4; ++r) {
                C[(size_t)(mbase + r) * NPK + n] =
                    acc0[i][j][r] + acc1[i][j][r] * (1.0f / 4096.0f) + bj;
            }
        }
    }
}

// ---------------------------------------------------------------------------
// Fallback fp32 GEMM (used only if ws_size can't hold the f16 pack buffers)
// ---------------------------------------------------------------------------
__global__ __launch_bounds__(256) void gemm_kernel(
    const int* __restrict__ tokens,
    const float* __restrict__ emb,
    const float* __restrict__ diags,
    const float* __restrict__ bias,
    float* __restrict__ C)
{
    __shared__ __align__(16) float As[16][132];
    __shared__ __align__(16) float Bs[16][132];
    __shared__ int rowbase[128];

    const int tid = threadIdx.x;
    const int n0 = blockIdx.x * 128;
    const int m0 = blockIdx.y * 128;

    if (tid < 128) rowbase[tid] = tokens[m0 + tid] * DD;
    __syncthreads();

    const int tx4 = (tid & 15) * 4;
    const int ty4 = (tid >> 4) * 4;
    const int r0  = tid >> 2;
    const int kq  = (tid & 3) * 4;

    float acc[8][8];
    #pragma unroll
    for (int i = 0; i < 8; ++i)
        #pragma unroll
        for (int j = 0; j < 8; ++j) acc[i][j] = 0.f;

    for (int kk = 0; kk < DD; kk += 16) {
        float4 a0, a1, b0, b1;
        const bool kval = (kk + kq) < DD;
        if (kval) {
            a0 = *(const float4*)(emb + rowbase[r0] + kk + kq);
            a1 = *(const float4*)(emb + rowbase[r0 + 64] + kk + kq);
            b0 = *(const float4*)(diags + (size_t)(n0 + r0) * DD + kk + kq);
            b1 = *(const float4*)(diags + (size_t)(n0 + r0 + 64) * DD + kk + kq);
        } else {
            a0 = make_float4(0.f, 0.f, 0.f, 0.f);
            a1 = a0; b0 = a0; b1 = a0;
        }
        __syncthreads();
        As[kq + 0][r0] = a0.x; As[kq + 1][r0] = a0.y; As[kq + 2][r0] = a0.z; As[kq + 3][r0] = a0.w;
        As[kq + 0][r0 + 64] = a1.x; As[kq + 1][r0 + 64] = a1.y; As[kq + 2][r0 + 64] = a1.z; As[kq + 3][r0 + 64] = a1.w;
        Bs[kq + 0][r0] = b0.x; Bs[kq + 1][r0] = b0.y; Bs[kq + 2][r0] = b0.z; Bs[kq + 3][r0] = b0.w;
        Bs[kq + 0][r0 + 64] = b1.x; Bs[kq + 1][r0 + 64] = b1.y; Bs[kq + 2][r0 + 64] = b1.z; Bs[kq + 3][r0 + 64] = b1.w;
        __syncthreads();
        #pragma unroll
        for (int k = 0; k < 16; ++k) {
            float4 av0 = *(const float4*)&As[k][ty4];
            float4 av1 = *(const float4*)&As[k][ty4 + 64];
            float4 bv0 = *(const float4*)&Bs[k][tx4];
            float4 bv1 = *(const float4*)&Bs[k][tx4 + 64];
            float a[8] = {av0.x, av0.y, av0.z, av0.w, av1.x, av1.y, av1.z, av1.w};
            float b[8] = {bv0.x, bv0.y, bv0.z, bv0.w, bv1.x, bv1.y, bv1.z, bv1.w};
            #pragma unroll
            for (int i = 0; i < 8; ++i)
                #pragma unroll
                for (int j = 0; j < 8; ++j)
                    acc[i][j] = fmaf(a[i], b[j], acc[i][j]);
        }
    }

    const float4 bias0 = *(const float4*)(bias + n0 + tx4);
    const float4 bias1 = *(const float4*)(bias + n0 + 64 + tx4);
    #pragma unroll
    for (int i = 0; i < 8; ++i) {
        const int m = m0 + ((i < 4) ? (ty4 + i) : (64 + ty4 + (i - 4)));
        float4 lo = make_float4(acc[i][0] + bias0.x, acc[i][1] + bias0.y,
                                acc[i][2] + bias0.z, acc[i][3] + bias0.w);
        float4 hi = make_float4(acc[i][4] + bias1.x, acc[i][5] + bias1.y,
                                acc[i][6] + bias1.z, acc[i][7] + bias1.w);
        *(float4*)(C + (size_t)m * NPK + n0 + tx4) = lo;
        *(float4*)(C + (size_t)m * NPK + n0 + 64 + tx4) = hi;
    }
}

// ---------------------------------------------------------------------------
// Phase 2: max-sum scan, one thread per (b,p), depth-4 register prefetch.
// ---------------------------------------------------------------------------
__global__ __launch_bounds__(64) void scan_kernel(
    const float* __restrict__ ts,
    const float* __restrict__ epsilons,
    const int* __restrict__ doc_lens,
    float* __restrict__ scores)
{
    const int b = blockIdx.x;
    const int p = blockIdx.y * 64 + threadIdx.x;
    const int dl = doc_lens[b];

    float e[6];
    #pragma unroll
    for (int i = 0; i < 6; ++i) e[i] = epsilons[p * 6 + i];

    const float* base = ts + (size_t)b * TT * NPK + p * 14;

    float h0 = 0.f, h1 = NEG, h2 = NEG, h3 = NEG, h4 = NEG, h5 = NEG, h6 = NEG;
    float sc = NEG;
    const bool end5 = (p < 256);

    float buf[4][14];

    auto load = [&](int slot, int t) {
        const float2* s = (const float2*)(base + (size_t)t * NPK);
        #pragma unroll
        for (int i = 0; i < 7; ++i) ((float2*)buf[slot])[i] = s[i];
    };
    auto step = [&](int slot, int t) {
        const float* tm = buf[slot];
        float ae0 = h0;
        float ae1 = fmaxf(h1, h0 + e[0]);
        float ae2 = fmaxf(h2, h1 + e[1]);
        float ae3 = fmaxf(h3, h2 + e[2]);
        float ae4 = fmaxf(h4, h3 + e[3]);
        float ae5 = fmaxf(h5, h4 + e[4]);
        float ae6 = fmaxf(h6, h5 + e[5]);
        h0 = fmaxf(0.f,          ae0 + tm[0]);
        h1 = fmaxf(ae0 + tm[7],  ae1 + tm[1]);
        h2 = fmaxf(ae1 + tm[8],  ae2 + tm[2]);
        h3 = fmaxf(ae2 + tm[9],  ae3 + tm[3]);
        h4 = fmaxf(ae3 + tm[10], ae4 + tm[4]);
        h5 = fmaxf(ae4 + tm[11], ae5 + tm[5]);
        h6 = fmaxf(ae5 + tm[12], ae6 + tm[6]);
        const float endv = end5 ? h5 : h6;
        if (t < dl) sc = fmaxf(sc, endv);
    };

    #pragma unroll
    for (int j = 0; j < 4; ++j) load(j, j);

    for (int tb = 0; tb < TT - 4; tb += 4) {
        #pragma unroll
        for (int j = 0; j < 4; ++j) {
            step(j, tb + j);
            load(j, tb + j + 4);
        }
    }
    #pragma unroll
    for (int j = 0; j < 4; ++j) step(j, TT - 4 + j);

    scores[p * BB + b] = sc;
}

// ---------------------------------------------------------------------------
// Phase 3: BatchNorm (batch stats) + sign(relu) + final linear. One block.
// ---------------------------------------------------------------------------
__global__ __launch_bounds__(512) void finalize_kernel(
    const float* __restrict__ scores,
    const float* __restrict__ bn_w,
    const float* __restrict__ bn_b,
    const float* __restrict__ fw,
    const float* __restrict__ fb,
    float* __restrict__ out)
{
    __shared__ float acc[64];
    const int p = threadIdx.x;
    if (p < 64) acc[p] = 0.f;
    __syncthreads();

    float x[32];
    const float4* sp = (const float4*)(scores + p * 32);
    #pragma unroll
    for (int i = 0; i < 8; ++i) ((float4*)x)[i] = sp[i];

    float mean = 0.f;
    #pragma unroll
    for (int i = 0; i < 32; ++i) mean += x[i];
    mean *= (1.f / 32.f);
    float var = 0.f;
    #pragma unroll
    for (int i = 0; i < 32; ++i) { const float d = x[i] - mean; var = fmaf(d, d, var); }
    var *= (1.f / 32.f);

    const float scale = (1.f / sqrtf(var + 1e-5f)) * bn_w[p];
    const float shift = bn_b[p];
    const float w0 = fw[p], w1 = fw[PP + p];

    for (int b = 0; b < 32; ++b) {
        const float v = (x[b] - mean) * scale + shift;
        const bool bin = v > 0.f;
        float v0 = bin ? w0 : 0.f;
        float v1 = bin ? w1 : 0.f;
        #pragma unroll
        for (int o = 32; o; o >>= 1) {
            v0 += __shfl_xor(v0, o);
            v1 += __shfl_xor(v1, o);
        }
        if ((threadIdx.x & 63) == 0) {
            atomicAdd(&acc[b * 2 + 0], v0);
            atomicAdd(&acc[b * 2 + 1], v1);
        }
    }
    __syncthreads();
    if (p < 64) out[p] = acc[p] + fb[p & 1];
}

// ---------------------------------------------------------------------------
extern "C" void kernel_launch(void* const* d_in, const int* in_sizes, int n_in,
                              void* d_out, int out_size, void* d_ws, size_t ws_size,
                              hipStream_t stream) {
    const int*   tokens   = (const int*)d_in[0];
    const int*   doc_lens = (const int*)d_in[1];
    const float* emb      = (const float*)d_in[2];
    const float* diags    = (const float*)d_in[3];
    const float* bias     = (const float*)d_in[4];
    const float* eps      = (const float*)d_in[5];
    const float* bnw      = (const float*)d_in[6];
    const float* bnb      = (const float*)d_in[7];
    const float* fw       = (const float*)d_in[8];
    const float* fb       = (const float*)d_in[9];
    float* out = (float*)d_out;

    float* ts     = (float*)d_ws;                    // [4096][7168] = 117.4 MB
    float* scores = ts + (size_t)4096 * NPK;         // [512][32]
    _Float16* Ah  = (_Float16*)(scores + PP * BB);   // [4096][320] f16 hi
    _Float16* Al  = Ah + (size_t)4096 * KP;          // [4096][320] f16 lo*4096
    _Float16* Bh  = Al + (size_t)4096 * KP;          // [7168][320]
    _Float16* Bl  = Bh + (size_t)NPK * KP;
    const size_t needed = (size_t)((char*)(Bl + (size_t)NPK * KP) - (char*)d_ws);

    if (ws_size >= needed) {
        pack_a_kernel<<<1280, 256, 0, stream>>>(tokens, emb, Ah, Al);
        pack_b_kernel<<<2240, 256, 0, stream>>>(diags, Bh, Bl);
        gemm_f16_kernel<<<dim3(56, 32), 256, 0, stream>>>(Ah, Al, Bh, Bl, bias, ts);
    } else {
        gemm_kernel<<<dim3(56, 32), 256, 0, stream>>>(tokens, emb, diags, bias, ts);
    }
    scan_kernel<<<dim3(32, 8), 64, 0, stream>>>(ts, eps, doc_lens, scores);
    finalize_kernel<<<1, 512, 0, stream>>>(scores, bnw, bnb, fw, fb, out);
}